// Round 13
// baseline (114.127 us; speedup 1.0000x reference)
//
#include <hip/hip_runtime.h>
#include <math.h>

#define D 768
#define DF2 384               // D / 2
#define DF4 192               // D / 4
#define NQ 128                // total queries
#define KPQ 784               // keys per query
#define NCHUNK 16             // key chunks per query
#define KCHUNK 49             // KPQ / NCHUNK

#define EXP2F(x) __builtin_amdgcn_exp2f(x)

__device__ __forceinline__ float dot4f(const float4 a, const float4 b) {
    return a.x * b.x + a.y * b.y + a.z * b.z + a.w * b.w;
}

// ---------------------------------------------------------------------------
// Transpose Wq, Wv, Wo (768x768) -> ws.  64x64 tiles, LDS +1 pad.  (proven R7)
// ---------------------------------------------------------------------------
__global__ __launch_bounds__(256) void k_tr(const float* __restrict__ Wq,
                                            const float* __restrict__ Wv,
                                            const float* __restrict__ Wo,
                                            float* __restrict__ WqT,
                                            float* __restrict__ WvT,
                                            float* __restrict__ WoT) {
    __shared__ float t[64][65];
    const float* src;
    float* dst;
    if (blockIdx.y == 0)      { src = Wq; dst = WqT; }
    else if (blockIdx.y == 1) { src = Wv; dst = WvT; }
    else                      { src = Wo; dst = WoT; }
    const int tr = blockIdx.x / 12, tc = blockIdx.x % 12;
    const int r0 = tr * 64, c0 = tc * 64;
    const int lr = threadIdx.x >> 6, lc = threadIdx.x & 63;
#pragma unroll
    for (int i = 0; i < 16; ++i)
        t[lr + i * 4][lc] = src[(size_t)(r0 + lr + i * 4) * D + c0 + lc];
    __syncthreads();
#pragma unroll
    for (int i = 0; i < 16; ++i)
        dst[(size_t)(c0 + lr + i * 4) * D + r0 + lc] = t[lc][lr + i * 4];
}

// ---------------------------------------------------------------------------
// Small GEMM, split-N x split-K (proven R7, Q=4, 192 blocks, 512 threads).
// Out[q][e] = sum_d A[q][d]*W[d][e] (+bias)(+res)(*scale).
// ---------------------------------------------------------------------------
template <bool BIAS, bool RES, bool SCALE>
__global__ __launch_bounds__(512) void k_gemm2(const float* __restrict__ A,
                                               const float2* __restrict__ W2,
                                               const float2* __restrict__ bias2,
                                               const float2* __restrict__ res2,
                                               float2* __restrict__ Out2) {
    __shared__ float2 part[8][4][64];
    const int ct  = blockIdx.x % 6;
    const int q0  = (blockIdx.x / 6) * 4;
    const int tid = threadIdx.x;
    const int ds  = __builtin_amdgcn_readfirstlane(tid >> 6);   // wave id 0..7
    const int c2  = tid & 63;
    const int e2  = ct * 64 + c2;
    const float* a0 = A + (size_t)q0 * D;
    const float* a1 = a0 + D;
    const float* a2 = a1 + D;
    const float* a3 = a2 + D;
    float2 acc0 = {0.f, 0.f}, acc1 = {0.f, 0.f}, acc2 = {0.f, 0.f}, acc3 = {0.f, 0.f};
    const int dbase = ds * 96;
#pragma unroll 8
    for (int i = 0; i < 96; ++i) {
        const int d = dbase + i;
        const float2 wv = W2[(size_t)d * DF2 + e2];
        const float x0 = a0[d], x1 = a1[d], x2 = a2[d], x3 = a3[d];
        acc0.x = fmaf(x0, wv.x, acc0.x); acc0.y = fmaf(x0, wv.y, acc0.y);
        acc1.x = fmaf(x1, wv.x, acc1.x); acc1.y = fmaf(x1, wv.y, acc1.y);
        acc2.x = fmaf(x2, wv.x, acc2.x); acc2.y = fmaf(x2, wv.y, acc2.y);
        acc3.x = fmaf(x3, wv.x, acc3.x); acc3.y = fmaf(x3, wv.y, acc3.y);
    }
    part[ds][0][c2] = acc0;
    part[ds][1][c2] = acc1;
    part[ds][2][c2] = acc2;
    part[ds][3][c2] = acc3;
    __syncthreads();
    if (tid < 256) {
        const int q = tid >> 6, c = tid & 63;
        float2 s = {0.f, 0.f};
#pragma unroll
        for (int p = 0; p < 8; ++p) {
            s.x += part[p][q][c].x;
            s.y += part[p][q][c].y;
        }
        if (BIAS) {
            const float2 b = bias2[ct * 64 + c];
            s.x += b.x; s.y += b.y;
        }
        if (RES) {
            const float2 r = res2[(size_t)(q0 + q) * DF2 + ct * 64 + c];
            s.x += r.x; s.y += r.y;
        }
        if (SCALE) {
            const float rsd2 = 0.036084391824351615f * 1.4426950408889634f; // 1/sqrt(768)*log2e
            s.x *= rsd2; s.y *= rsd2;
        }
        Out2[(size_t)(q0 + q) * DF2 + ct * 64 + c] = s;
    }
}

// ---------------------------------------------------------------------------
// Flash pass (no max-tracking; scores tiny).  qt pre-scaled in the qt GEMM.
// One block per (query, key-chunk of 49); 4 waves; 4 rows/iter/wave + tail.
// HR read exactly once.  (proven R12)
// ---------------------------------------------------------------------------
__global__ __launch_bounds__(256) void k_flash(const float4* __restrict__ HR,
                                               const float4* __restrict__ qt,
                                               float4* __restrict__ Cpart,
                                               float* __restrict__ Lp) {
    const int b     = blockIdx.x;
    const int qi    = b >> 4;
    const int chunk = b & 15;
    const size_t rowbase = (size_t)qi * KPQ + (size_t)chunk * KCHUNK;
    const int tid  = threadIdx.x;
    const int w    = tid >> 6;
    const int lane = tid & 63;

    const float4 qa = qt[qi * DF4 + lane];
    const float4 qb = qt[qi * DF4 + lane + 64];
    const float4 qc = qt[qi * DF4 + lane + 128];

    float l = 0.f;
    float4 c0 = make_float4(0.f, 0.f, 0.f, 0.f);
    float4 c1 = make_float4(0.f, 0.f, 0.f, 0.f);
    float4 c2 = make_float4(0.f, 0.f, 0.f, 0.f);

    int j = w;
    while (j + 12 < KCHUNK) {
        const float4* rA = HR + (rowbase + (size_t)j) * DF4;
        const float4* rB = HR + (rowbase + (size_t)(j + 4)) * DF4;
        const float4* rF = HR + (rowbase + (size_t)(j + 8)) * DF4;
        const float4* rG = HR + (rowbase + (size_t)(j + 12)) * DF4;
        const float4 a0 = rA[lane], a1 = rA[lane + 64], a2 = rA[lane + 128];
        const float4 b0 = rB[lane], b1 = rB[lane + 64], b2 = rB[lane + 128];
        const float4 f0 = rF[lane], f1 = rF[lane + 64], f2 = rF[lane + 128];
        const float4 g0 = rG[lane], g1 = rG[lane + 64], g2 = rG[lane + 128];
        float p1 = dot4f(qa, a0) + dot4f(qb, a1) + dot4f(qc, a2);
        float p2 = dot4f(qa, b0) + dot4f(qb, b1) + dot4f(qc, b2);
        float p3 = dot4f(qa, f0) + dot4f(qb, f1) + dot4f(qc, f2);
        float p4 = dot4f(qa, g0) + dot4f(qb, g1) + dot4f(qc, g2);
#pragma unroll
        for (int off = 32; off; off >>= 1) {
            p1 += __shfl_xor(p1, off, 64);
            p2 += __shfl_xor(p2, off, 64);
            p3 += __shfl_xor(p3, off, 64);
            p4 += __shfl_xor(p4, off, 64);
        }
        const float e1 = EXP2F(p1);
        const float e2 = EXP2F(p2);
        const float e3 = EXP2F(p3);
        const float e4 = EXP2F(p4);
        l += (e1 + e2) + (e3 + e4);
        c0.x = fmaf(e1, a0.x, fmaf(e2, b0.x, fmaf(e3, f0.x, fmaf(e4, g0.x, c0.x))));
        c0.y = fmaf(e1, a0.y, fmaf(e2, b0.y, fmaf(e3, f0.y, fmaf(e4, g0.y, c0.y))));
        c0.z = fmaf(e1, a0.z, fmaf(e2, b0.z, fmaf(e3, f0.z, fmaf(e4, g0.z, c0.z))));
        c0.w = fmaf(e1, a0.w, fmaf(e2, b0.w, fmaf(e3, f0.w, fmaf(e4, g0.w, c0.w))));
        c1.x = fmaf(e1, a1.x, fmaf(e2, b1.x, fmaf(e3, f1.x, fmaf(e4, g1.x, c1.x))));
        c1.y = fmaf(e1, a1.y, fmaf(e2, b1.y, fmaf(e3, f1.y, fmaf(e4, g1.y, c1.y))));
        c1.z = fmaf(e1, a1.z, fmaf(e2, b1.z, fmaf(e3, f1.z, fmaf(e4, g1.z, c1.z))));
        c1.w = fmaf(e1, a1.w, fmaf(e2, b1.w, fmaf(e3, f1.w, fmaf(e4, g1.w, c1.w))));
        c2.x = fmaf(e1, a2.x, fmaf(e2, b2.x, fmaf(e3, f2.x, fmaf(e4, g2.x, c2.x))));
        c2.y = fmaf(e1, a2.y, fmaf(e2, b2.y, fmaf(e3, f2.y, fmaf(e4, g2.y, c2.y))));
        c2.z = fmaf(e1, a2.z, fmaf(e2, b2.z, fmaf(e3, f2.z, fmaf(e4, g2.z, c2.z))));
        c2.w = fmaf(e1, a2.w, fmaf(e2, b2.w, fmaf(e3, f2.w, fmaf(e4, g2.w, c2.w))));
        j += 16;
    }
    while (j < KCHUNK) {
        const float4* rA = HR + (rowbase + (size_t)j) * DF4;
        const float4 a0 = rA[lane], a1 = rA[lane + 64], a2 = rA[lane + 128];
        float p1 = dot4f(qa, a0) + dot4f(qb, a1) + dot4f(qc, a2);
#pragma unroll
        for (int off = 32; off; off >>= 1) p1 += __shfl_xor(p1, off, 64);
        const float e1 = EXP2F(p1);
        l += e1;
        c0.x = fmaf(e1, a0.x, c0.x); c0.y = fmaf(e1, a0.y, c0.y);
        c0.z = fmaf(e1, a0.z, c0.z); c0.w = fmaf(e1, a0.w, c0.w);
        c1.x = fmaf(e1, a1.x, c1.x); c1.y = fmaf(e1, a1.y, c1.y);
        c1.z = fmaf(e1, a1.z, c1.z); c1.w = fmaf(e1, a1.w, c1.w);
        c2.x = fmaf(e1, a2.x, c2.x); c2.y = fmaf(e1, a2.y, c2.y);
        c2.z = fmaf(e1, a2.z, c2.z); c2.w = fmaf(e1, a2.w, c2.w);
        j += 4;
    }

    __shared__ __align__(16) float4 c_lds[4][DF4];
    __shared__ float l_lds[4];
    c_lds[w][lane]       = c0;
    c_lds[w][lane + 64]  = c1;
    c_lds[w][lane + 128] = c2;
    if (lane == 0) l_lds[w] = l;
    __syncthreads();

    if (tid < DF4) {
        float4 cc = make_float4(0.f, 0.f, 0.f, 0.f);
#pragma unroll
        for (int p = 0; p < 4; ++p) {
            const float4 cv = c_lds[p][tid];
            cc.x += cv.x; cc.y += cv.y; cc.z += cv.z; cc.w += cv.w;
        }
        Cpart[(size_t)b * DF4 + tid] = cc;
        if (tid == 0) Lp[b] = l_lds[0] + l_lds[1] + l_lds[2] + l_lds[3];
    }
}

// ---------------------------------------------------------------------------
// Fused combine + X = (Cn/L) @ WvT + bv.  grid 192 blocks, 512 threads.
// Prologue: cn rows summed from Cpart (shared ref 0 -> plain sum) -> cnbuf
// in GLOBAL (dup-written by the 6 ct-blocks of a q-group -- identical values,
// benign).  GEMM A-broadcasts via uniform VMEM loads of cnbuf (same-block RAW
// after __syncthreads -- pattern verified correct in R8).  1/L folded into
// the epilogue by GEMM linearity.
// ---------------------------------------------------------------------------
__global__ __launch_bounds__(512) void k_gemmV(const float4* __restrict__ Cpart4,
                                               const float* __restrict__ Lp,
                                               const float2* __restrict__ WvT2,
                                               const float2* __restrict__ bv2,
                                               float* __restrict__ cnbuf,
                                               float2* __restrict__ Xbuf2) {
    __shared__ float2 part[8][4][64];
    const int ct  = blockIdx.x % 6;
    const int q0  = (blockIdx.x / 6) * 4;
    const int tid = threadIdx.x;

    // prologue: cn = sum of chunk partials (no normalization yet)
    for (int f = tid; f < 4 * DF4; f += 512) {
        const int q = f / DF4, ff = f % DF4;
        float4 s = make_float4(0.f, 0.f, 0.f, 0.f);
#pragma unroll
        for (int p = 0; p < NCHUNK; ++p) {
            const float4 v = Cpart4[(size_t)((q0 + q) * NCHUNK + p) * DF4 + ff];
            s.x += v.x; s.y += v.y; s.z += v.z; s.w += v.w;
        }
        *reinterpret_cast<float4*>(&cnbuf[(size_t)(q0 + q) * D + ff * 4]) = s;
    }
    float invL[4];
#pragma unroll
    for (int q = 0; q < 4; ++q) {
        float L = 0.f;
#pragma unroll
        for (int p = 0; p < NCHUNK; ++p) L += Lp[(q0 + q) * NCHUNK + p];
        invL[q] = 1.f / L;
    }
    __syncthreads();   // cnbuf stores drained; GEMM reads block's own writes

    const int ds = __builtin_amdgcn_readfirstlane(tid >> 6);
    const int c2 = tid & 63;
    const int e2 = ct * 64 + c2;
    const float* a0 = cnbuf + (size_t)q0 * D;
    const float* a1 = a0 + D;
    const float* a2 = a1 + D;
    const float* a3 = a2 + D;
    float2 acc0 = {0.f, 0.f}, acc1 = {0.f, 0.f}, acc2 = {0.f, 0.f}, acc3 = {0.f, 0.f};
    const int dbase = ds * 96;
#pragma unroll 8
    for (int i = 0; i < 96; ++i) {
        const int d = dbase + i;
        const float2 wv = WvT2[(size_t)d * DF2 + e2];
        const float x0 = a0[d], x1 = a1[d], x2 = a2[d], x3 = a3[d];
        acc0.x = fmaf(x0, wv.x, acc0.x); acc0.y = fmaf(x0, wv.y, acc0.y);
        acc1.x = fmaf(x1, wv.x, acc1.x); acc1.y = fmaf(x1, wv.y, acc1.y);
        acc2.x = fmaf(x2, wv.x, acc2.x); acc2.y = fmaf(x2, wv.y, acc2.y);
        acc3.x = fmaf(x3, wv.x, acc3.x); acc3.y = fmaf(x3, wv.y, acc3.y);
    }
    part[ds][0][c2] = acc0;
    part[ds][1][c2] = acc1;
    part[ds][2][c2] = acc2;
    part[ds][3][c2] = acc3;
    __syncthreads();
    if (tid < 256) {
        const int q = tid >> 6, c = tid & 63;
        float2 s = {0.f, 0.f};
#pragma unroll
        for (int p = 0; p < 8; ++p) {
            s.x += part[p][q][c].x;
            s.y += part[p][q][c].y;
        }
        const float2 b = bv2[ct * 64 + c];
        s.x = s.x * invL[q] + b.x;
        s.y = s.y * invL[q] + b.y;
        Xbuf2[(size_t)(q0 + q) * DF2 + ct * 64 + c] = s;
    }
}

// ---------------------------------------------------------------------------
// LayerNorm: one block per query (256 threads, 3 elems each).
// ---------------------------------------------------------------------------
__global__ __launch_bounds__(256) void k_ln(const float* __restrict__ y,
                                            const float* __restrict__ gamma,
                                            const float* __restrict__ beta,
                                            float* __restrict__ out) {
    __shared__ float sp[4], ssp[4];
    const int qi = blockIdx.x;
    const int tid = threadIdx.x, w = tid >> 6, lane = tid & 63;
    const float* yr = y + (size_t)qi * D;
    const float v0 = yr[tid], v1 = yr[tid + 256], v2 = yr[tid + 512];
    float s  = v0 + v1 + v2;
    float ss = v0 * v0 + v1 * v1 + v2 * v2;
#pragma unroll
    for (int off = 32; off; off >>= 1) {
        s  += __shfl_xor(s, off, 64);
        ss += __shfl_xor(ss, off, 64);
    }
    if (lane == 0) { sp[w] = s; ssp[w] = ss; }
    __syncthreads();
    s  = sp[0] + sp[1] + sp[2] + sp[3];
    ss = ssp[0] + ssp[1] + ssp[2] + ssp[3];
    const float mu  = s * (1.f / 768.f);
    const float var = ss * (1.f / 768.f) - mu * mu;
    const float rs  = rsqrtf(var + 1e-5f);
    float* o = out + (size_t)qi * D;
    o[tid]       = (v0 - mu) * rs * gamma[tid]       + beta[tid];
    o[tid + 256] = (v1 - mu) * rs * gamma[tid + 256] + beta[tid + 256];
    o[tid + 512] = (v2 - mu) * rs * gamma[tid + 512] + beta[tid + 512];
}

extern "C" void kernel_launch(void* const* d_in, const int* in_sizes, int n_in,
                              void* d_out, int out_size, void* d_ws, size_t ws_size,
                              hipStream_t stream) {
    const float* LR    = (const float*)d_in[0];
    const float* HR    = (const float*)d_in[1];
    const float* Wq    = (const float*)d_in[2];
    const float* bq    = (const float*)d_in[3];
    const float* Wk    = (const float*)d_in[4];
    // d_in[5] = bk: unused (per-query constant on all scores; softmax-invariant)
    const float* Wv    = (const float*)d_in[6];
    const float* bv    = (const float*)d_in[7];
    const float* Wo    = (const float*)d_in[8];
    const float* bo    = (const float*)d_in[9];
    const float* gamma = (const float*)d_in[10];
    const float* beta  = (const float*)d_in[11];
    float* out = (float*)d_out;

    float* ws = (float*)d_ws;
    float* WqT   = ws;                  // 589824
    float* WvT   = ws + 589824;         // 589824
    float* WoT   = ws + 1179648;        // 589824
    float* qbuf  = ws + 1769472;        // 98304
    float* qtbuf = ws + 1867776;        // 98304
    float* Cpart = ws + 1966080;        // 2048*768 = 1572864
    float* Lp    = ws + 3538944;        // 2048
    float* cnbuf = ws + 3540992;        // 98304
    float* Xbuf  = ws + 3639296;        // 98304
    float* ybuf  = ws + 3737600;        // 98304

    // transpose Wq, Wv, Wo
    k_tr<<<dim3(144, 3), 256, 0, stream>>>(Wq, Wv, Wo, WqT, WvT, WoT);
    // q = LR @ Wq^T + bq
    k_gemm2<true, false, false><<<192, 512, 0, stream>>>(
        LR, (const float2*)WqT, (const float2*)bq, nullptr, (float2*)qbuf);
    // qt = (q @ Wk) * 1/sqrt(d)*log2e  (scale folded in)
    k_gemm2<false, false, true><<<192, 512, 0, stream>>>(
        qbuf, (const float2*)Wk, nullptr, nullptr, (float2*)qtbuf);
    // flash pass over HR (no max-tracking; shared reference 0)
    k_flash<<<NQ * NCHUNK, 256, 0, stream>>>((const float4*)HR, (const float4*)qtbuf,
                                             (float4*)Cpart, Lp);
    // combine + X = (Cn/L) @ Wv^T + bv  (fused)
    k_gemmV<<<192, 512, 0, stream>>>((const float4*)Cpart, Lp,
                                     (const float2*)WvT, (const float2*)bv,
                                     cnbuf, (float2*)Xbuf);
    // y = q + X @ Wo^T + bo
    k_gemm2<true, true, false><<<192, 512, 0, stream>>>(
        Xbuf, (const float2*)WoT, (const float2*)bo, (const float2*)qbuf, (float2*)ybuf);
    // LayerNorm
    k_ln<<<NQ, 256, 0, stream>>>(ybuf, gamma, beta, out);
}

// Round 14
// 104.892 us; speedup vs baseline: 1.0880x; 1.0880x over previous
//
#include <hip/hip_runtime.h>
#include <math.h>

#define D 768
#define DF2 384               // D / 2
#define DF4 192               // D / 4
#define NQ 128                // total queries
#define KPQ 784               // keys per query
#define NCHUNK 16             // key chunks per query
#define KCHUNK 49             // KPQ / NCHUNK

#define EXP2F(x) __builtin_amdgcn_exp2f(x)

__device__ __forceinline__ float dot4f(const float4 a, const float4 b) {
    return a.x * b.x + a.y * b.y + a.z * b.z + a.w * b.w;
}

// ---------------------------------------------------------------------------
// Transpose Wq, Wv, Wo (768x768) -> ws.  64x64 tiles, LDS +1 pad.  (proven R7)
// ---------------------------------------------------------------------------
__global__ __launch_bounds__(256) void k_tr(const float* __restrict__ Wq,
                                            const float* __restrict__ Wv,
                                            const float* __restrict__ Wo,
                                            float* __restrict__ WqT,
                                            float* __restrict__ WvT,
                                            float* __restrict__ WoT) {
    __shared__ float t[64][65];
    const float* src;
    float* dst;
    if (blockIdx.y == 0)      { src = Wq; dst = WqT; }
    else if (blockIdx.y == 1) { src = Wv; dst = WvT; }
    else                      { src = Wo; dst = WoT; }
    const int tr = blockIdx.x / 12, tc = blockIdx.x % 12;
    const int r0 = tr * 64, c0 = tc * 64;
    const int lr = threadIdx.x >> 6, lc = threadIdx.x & 63;
#pragma unroll
    for (int i = 0; i < 16; ++i)
        t[lr + i * 4][lc] = src[(size_t)(r0 + lr + i * 4) * D + c0 + lc];
    __syncthreads();
#pragma unroll
    for (int i = 0; i < 16; ++i)
        dst[(size_t)(c0 + lr + i * 4) * D + r0 + lc] = t[lc][lr + i * 4];
}

// ---------------------------------------------------------------------------
// Small GEMM, split-N x split-K (proven R7, Q=4, 192 blocks, 512 threads).
// Out[q][e] = sum_d A[q][d]*W[d][e] (+bias)(+res)(*scale).
// ---------------------------------------------------------------------------
template <bool BIAS, bool RES, bool SCALE>
__global__ __launch_bounds__(512) void k_gemm2(const float* __restrict__ A,
                                               const float2* __restrict__ W2,
                                               const float2* __restrict__ bias2,
                                               const float2* __restrict__ res2,
                                               float2* __restrict__ Out2) {
    __shared__ float2 part[8][4][64];
    const int ct  = blockIdx.x % 6;
    const int q0  = (blockIdx.x / 6) * 4;
    const int tid = threadIdx.x;
    const int ds  = __builtin_amdgcn_readfirstlane(tid >> 6);   // wave id 0..7
    const int c2  = tid & 63;
    const int e2  = ct * 64 + c2;
    const float* a0 = A + (size_t)q0 * D;
    const float* a1 = a0 + D;
    const float* a2 = a1 + D;
    const float* a3 = a2 + D;
    float2 acc0 = {0.f, 0.f}, acc1 = {0.f, 0.f}, acc2 = {0.f, 0.f}, acc3 = {0.f, 0.f};
    const int dbase = ds * 96;
#pragma unroll 8
    for (int i = 0; i < 96; ++i) {
        const int d = dbase + i;
        const float2 wv = W2[(size_t)d * DF2 + e2];
        const float x0 = a0[d], x1 = a1[d], x2 = a2[d], x3 = a3[d];
        acc0.x = fmaf(x0, wv.x, acc0.x); acc0.y = fmaf(x0, wv.y, acc0.y);
        acc1.x = fmaf(x1, wv.x, acc1.x); acc1.y = fmaf(x1, wv.y, acc1.y);
        acc2.x = fmaf(x2, wv.x, acc2.x); acc2.y = fmaf(x2, wv.y, acc2.y);
        acc3.x = fmaf(x3, wv.x, acc3.x); acc3.y = fmaf(x3, wv.y, acc3.y);
    }
    part[ds][0][c2] = acc0;
    part[ds][1][c2] = acc1;
    part[ds][2][c2] = acc2;
    part[ds][3][c2] = acc3;
    __syncthreads();
    if (tid < 256) {
        const int q = tid >> 6, c = tid & 63;
        float2 s = {0.f, 0.f};
#pragma unroll
        for (int p = 0; p < 8; ++p) {
            s.x += part[p][q][c].x;
            s.y += part[p][q][c].y;
        }
        if (BIAS) {
            const float2 b = bias2[ct * 64 + c];
            s.x += b.x; s.y += b.y;
        }
        if (RES) {
            const float2 r = res2[(size_t)(q0 + q) * DF2 + ct * 64 + c];
            s.x += r.x; s.y += r.y;
        }
        if (SCALE) {
            const float rsd2 = 0.036084391824351615f * 1.4426950408889634f; // 1/sqrt(768)*log2e
            s.x *= rsd2; s.y *= rsd2;
        }
        Out2[(size_t)(q0 + q) * DF2 + ct * 64 + c] = s;
    }
}

// ---------------------------------------------------------------------------
// Flash pass, 16-lanes-per-row variant.  No max-tracking (scores tiny; qt
// pre-scaled by 1/sqrt(d)*log2e in the qt GEMM).  Per wave-iter: 4 rows,
// lane-group g (16 lanes) owns row j+g, lane covers f4 cols {lg+16k}.
// Dot-reduce = 4 shuffle levels shared by all 4 rows (was 6 levels/row).
// OOB tail rows clamped in-bounds with e=0.  HR read exactly once.
// ---------------------------------------------------------------------------
__global__ __launch_bounds__(256) void k_flash(const float4* __restrict__ HR,
                                               const float4* __restrict__ qt,
                                               float4* __restrict__ Cpart,
                                               float* __restrict__ Lp) {
    const int b     = blockIdx.x;
    const int qi    = b >> 4;
    const int chunk = b & 15;
    const size_t rowbase = (size_t)qi * KPQ + (size_t)chunk * KCHUNK;
    const int tid  = threadIdx.x;
    const int w    = tid >> 6;
    const int lane = tid & 63;
    const int g    = lane >> 4;     // row-group 0..3
    const int lg   = lane & 15;     // lane within group

    float4 qf[12];
#pragma unroll
    for (int k = 0; k < 12; ++k) qf[k] = qt[qi * DF4 + lg + 16 * k];

    float l = 0.f;
    float4 acc[12];
#pragma unroll
    for (int k = 0; k < 12; ++k) acc[k] = make_float4(0.f, 0.f, 0.f, 0.f);

    for (int j = 4 * w; j < KCHUNK; j += 16) {
        const int row  = j + g;
        const bool ok  = row < KCHUNK;
        const int srow = ok ? row : (KCHUNK - 1);
        const float4* rp = HR + (rowbase + (size_t)srow) * DF4;
        float4 v[12];
#pragma unroll
        for (int k = 0; k < 12; ++k) v[k] = rp[lg + 16 * k];
        float p = 0.f;
#pragma unroll
        for (int k = 0; k < 12; ++k) p += dot4f(qf[k], v[k]);
        // reduce within 16-lane group (xor<16 stays in-group)
#pragma unroll
        for (int off = 1; off < 16; off <<= 1) p += __shfl_xor(p, off, 64);
        const float e = ok ? EXP2F(p) : 0.f;
        l += e;
#pragma unroll
        for (int k = 0; k < 12; ++k) {
            acc[k].x = fmaf(e, v[k].x, acc[k].x);
            acc[k].y = fmaf(e, v[k].y, acc[k].y);
            acc[k].z = fmaf(e, v[k].z, acc[k].z);
            acc[k].w = fmaf(e, v[k].w, acc[k].w);
        }
    }
    // sum l across the 4 groups (16 lanes of a group hold identical l)
    l += __shfl_xor(l, 16, 64);
    l += __shfl_xor(l, 32, 64);

    __shared__ __align__(16) float4 c_lds[4][4][DF4];   // [wave][group][colf4]
    __shared__ float l_lds[4];
#pragma unroll
    for (int k = 0; k < 12; ++k) c_lds[w][g][lg + 16 * k] = acc[k];
    if (lane == 0) l_lds[w] = l;
    __syncthreads();

    if (tid < DF4) {
        float4 cc = make_float4(0.f, 0.f, 0.f, 0.f);
#pragma unroll
        for (int ww = 0; ww < 4; ++ww)
#pragma unroll
            for (int gg = 0; gg < 4; ++gg) {
                const float4 cv = c_lds[ww][gg][tid];
                cc.x += cv.x; cc.y += cv.y; cc.z += cv.z; cc.w += cv.w;
            }
        Cpart[(size_t)b * DF4 + tid] = cc;
        if (tid == 0) Lp[b] = l_lds[0] + l_lds[1] + l_lds[2] + l_lds[3];
    }
}

// ---------------------------------------------------------------------------
// Combine: all chunk partials share reference 0 -> plain sums, then divide.
// ---------------------------------------------------------------------------
__global__ __launch_bounds__(192) void k_combine(const float4* __restrict__ Cpart,
                                                 const float* __restrict__ Lp,
                                                 float4* __restrict__ Cn) {
    const int qi = blockIdx.x;
    const int f  = threadIdx.x;
    float L = 0.f;
#pragma unroll
    for (int p = 0; p < NCHUNK; ++p) L += Lp[qi * NCHUNK + p];
    float4 c = make_float4(0.f, 0.f, 0.f, 0.f);
#pragma unroll
    for (int p = 0; p < NCHUNK; ++p) {
        const float4 v = Cpart[(size_t)(qi * NCHUNK + p) * DF4 + f];
        c.x += v.x; c.y += v.y; c.z += v.z; c.w += v.w;
    }
    const float inv = 1.f / L;
    c.x *= inv; c.y *= inv; c.z *= inv; c.w *= inv;
    Cn[(size_t)qi * DF4 + f] = c;
}

// ---------------------------------------------------------------------------
// LayerNorm: one block per query (256 threads, 3 elems each).
// ---------------------------------------------------------------------------
__global__ __launch_bounds__(256) void k_ln(const float* __restrict__ y,
                                            const float* __restrict__ gamma,
                                            const float* __restrict__ beta,
                                            float* __restrict__ out) {
    __shared__ float sp[4], ssp[4];
    const int qi = blockIdx.x;
    const int tid = threadIdx.x, w = tid >> 6, lane = tid & 63;
    const float* yr = y + (size_t)qi * D;
    const float v0 = yr[tid], v1 = yr[tid + 256], v2 = yr[tid + 512];
    float s  = v0 + v1 + v2;
    float ss = v0 * v0 + v1 * v1 + v2 * v2;
#pragma unroll
    for (int off = 32; off; off >>= 1) {
        s  += __shfl_xor(s, off, 64);
        ss += __shfl_xor(ss, off, 64);
    }
    if (lane == 0) { sp[w] = s; ssp[w] = ss; }
    __syncthreads();
    s  = sp[0] + sp[1] + sp[2] + sp[3];
    ss = ssp[0] + ssp[1] + ssp[2] + ssp[3];
    const float mu  = s * (1.f / 768.f);
    const float var = ss * (1.f / 768.f) - mu * mu;
    const float rs  = rsqrtf(var + 1e-5f);
    float* o = out + (size_t)qi * D;
    o[tid]       = (v0 - mu) * rs * gamma[tid]       + beta[tid];
    o[tid + 256] = (v1 - mu) * rs * gamma[tid + 256] + beta[tid + 256];
    o[tid + 512] = (v2 - mu) * rs * gamma[tid + 512] + beta[tid + 512];
}

extern "C" void kernel_launch(void* const* d_in, const int* in_sizes, int n_in,
                              void* d_out, int out_size, void* d_ws, size_t ws_size,
                              hipStream_t stream) {
    const float* LR    = (const float*)d_in[0];
    const float* HR    = (const float*)d_in[1];
    const float* Wq    = (const float*)d_in[2];
    const float* bq    = (const float*)d_in[3];
    const float* Wk    = (const float*)d_in[4];
    // d_in[5] = bk: unused (per-query constant on all scores; softmax-invariant)
    const float* Wv    = (const float*)d_in[6];
    const float* bv    = (const float*)d_in[7];
    const float* Wo    = (const float*)d_in[8];
    const float* bo    = (const float*)d_in[9];
    const float* gamma = (const float*)d_in[10];
    const float* beta  = (const float*)d_in[11];
    float* out = (float*)d_out;

    float* ws = (float*)d_ws;
    float* WqT   = ws;                  // 589824
    float* WvT   = ws + 589824;         // 589824
    float* WoT   = ws + 1179648;        // 589824
    float* qbuf  = ws + 1769472;        // 98304
    float* qtbuf = ws + 1867776;        // 98304
    float* Cpart = ws + 1966080;        // 2048*768 = 1572864
    float* Lp    = ws + 3538944;        // 2048
    float* Cn    = ws + 3540992;        // 98304
    float* Xbuf  = ws + 3639296;        // 98304
    float* ybuf  = ws + 3737600;        // 98304

    // transpose Wq, Wv, Wo
    k_tr<<<dim3(144, 3), 256, 0, stream>>>(Wq, Wv, Wo, WqT, WvT, WoT);
    // q = LR @ Wq^T + bq
    k_gemm2<true, false, false><<<192, 512, 0, stream>>>(
        LR, (const float2*)WqT, (const float2*)bq, nullptr, (float2*)qbuf);
    // qt = (q @ Wk) * 1/sqrt(d)*log2e  (scale folded in)
    k_gemm2<false, false, true><<<192, 512, 0, stream>>>(
        qbuf, (const float2*)Wk, nullptr, nullptr, (float2*)qtbuf);
    // flash pass over HR (no max-tracking; shared reference 0)
    k_flash<<<NQ * NCHUNK, 256, 0, stream>>>((const float4*)HR, (const float4*)qtbuf,
                                             (float4*)Cpart, Lp);
    // combine chunk partials -> Cn
    k_combine<<<NQ, 192, 0, stream>>>((const float4*)Cpart, Lp, (float4*)Cn);
    // X = Cn @ Wv^T + bv
    k_gemm2<true, false, false><<<192, 512, 0, stream>>>(
        Cn, (const float2*)WvT, (const float2*)bv, nullptr, (float2*)Xbuf);
    // y = q + X @ Wo^T + bo
    k_gemm2<true, true, false><<<192, 512, 0, stream>>>(
        Xbuf, (const float2*)WoT, (const float2*)bo, (const float2*)qbuf, (float2*)ybuf);
    // LayerNorm
    k_ln<<<NQ, 256, 0, stream>>>(ybuf, gamma, beta, out);
}

// Round 15
// 101.214 us; speedup vs baseline: 1.1276x; 1.0363x over previous
//
#include <hip/hip_runtime.h>
#include <math.h>

#define D 768
#define DF2 384               // D / 2
#define DF4 192               // D / 4
#define NQ 128                // total queries
#define KPQ 784               // keys per query
#define NCHUNK 8              // key chunks per query
#define KCHUNK 98             // KPQ / NCHUNK

#define EXP2F(x) __builtin_amdgcn_exp2f(x)

__device__ __forceinline__ float dot4f(const float4 a, const float4 b) {
    return a.x * b.x + a.y * b.y + a.z * b.z + a.w * b.w;
}

// ---------------------------------------------------------------------------
// Transpose Wq, Wv, Wo (768x768) -> ws.  64x64 tiles, LDS +1 pad.  (proven R7)
// ---------------------------------------------------------------------------
__global__ __launch_bounds__(256) void k_tr(const float* __restrict__ Wq,
                                            const float* __restrict__ Wv,
                                            const float* __restrict__ Wo,
                                            float* __restrict__ WqT,
                                            float* __restrict__ WvT,
                                            float* __restrict__ WoT) {
    __shared__ float t[64][65];
    const float* src;
    float* dst;
    if (blockIdx.y == 0)      { src = Wq; dst = WqT; }
    else if (blockIdx.y == 1) { src = Wv; dst = WvT; }
    else                      { src = Wo; dst = WoT; }
    const int tr = blockIdx.x / 12, tc = blockIdx.x % 12;
    const int r0 = tr * 64, c0 = tc * 64;
    const int lr = threadIdx.x >> 6, lc = threadIdx.x & 63;
#pragma unroll
    for (int i = 0; i < 16; ++i)
        t[lr + i * 4][lc] = src[(size_t)(r0 + lr + i * 4) * D + c0 + lc];
    __syncthreads();
#pragma unroll
    for (int i = 0; i < 16; ++i)
        dst[(size_t)(c0 + lr + i * 4) * D + r0 + lc] = t[lc][lr + i * 4];
}

// ---------------------------------------------------------------------------
// Small GEMM, split-N x split-K (proven R7, Q=4, 192 blocks, 512 threads).
// Out[q][e] = sum_d A[q][d]*W[d][e] (+bias)(+res)(*scale).
// ---------------------------------------------------------------------------
template <bool BIAS, bool RES, bool SCALE>
__global__ __launch_bounds__(512) void k_gemm2(const float* __restrict__ A,
                                               const float2* __restrict__ W2,
                                               const float2* __restrict__ bias2,
                                               const float2* __restrict__ res2,
                                               float2* __restrict__ Out2) {
    __shared__ float2 part[8][4][64];
    const int ct  = blockIdx.x % 6;
    const int q0  = (blockIdx.x / 6) * 4;
    const int tid = threadIdx.x;
    const int ds  = __builtin_amdgcn_readfirstlane(tid >> 6);   // wave id 0..7
    const int c2  = tid & 63;
    const int e2  = ct * 64 + c2;
    const float* a0 = A + (size_t)q0 * D;
    const float* a1 = a0 + D;
    const float* a2 = a1 + D;
    const float* a3 = a2 + D;
    float2 acc0 = {0.f, 0.f}, acc1 = {0.f, 0.f}, acc2 = {0.f, 0.f}, acc3 = {0.f, 0.f};
    const int dbase = ds * 96;
#pragma unroll 8
    for (int i = 0; i < 96; ++i) {
        const int d = dbase + i;
        const float2 wv = W2[(size_t)d * DF2 + e2];
        const float x0 = a0[d], x1 = a1[d], x2 = a2[d], x3 = a3[d];
        acc0.x = fmaf(x0, wv.x, acc0.x); acc0.y = fmaf(x0, wv.y, acc0.y);
        acc1.x = fmaf(x1, wv.x, acc1.x); acc1.y = fmaf(x1, wv.y, acc1.y);
        acc2.x = fmaf(x2, wv.x, acc2.x); acc2.y = fmaf(x2, wv.y, acc2.y);
        acc3.x = fmaf(x3, wv.x, acc3.x); acc3.y = fmaf(x3, wv.y, acc3.y);
    }
    part[ds][0][c2] = acc0;
    part[ds][1][c2] = acc1;
    part[ds][2][c2] = acc2;
    part[ds][3][c2] = acc3;
    __syncthreads();
    if (tid < 256) {
        const int q = tid >> 6, c = tid & 63;
        float2 s = {0.f, 0.f};
#pragma unroll
        for (int p = 0; p < 8; ++p) {
            s.x += part[p][q][c].x;
            s.y += part[p][q][c].y;
        }
        if (BIAS) {
            const float2 b = bias2[ct * 64 + c];
            s.x += b.x; s.y += b.y;
        }
        if (RES) {
            const float2 r = res2[(size_t)(q0 + q) * DF2 + ct * 64 + c];
            s.x += r.x; s.y += r.y;
        }
        if (SCALE) {
            const float rsd2 = 0.036084391824351615f * 1.4426950408889634f; // 1/sqrt(768)*log2e
            s.x *= rsd2; s.y *= rsd2;
        }
        Out2[(size_t)(q0 + q) * DF2 + ct * 64 + c] = s;
    }
}

// ---------------------------------------------------------------------------
// Flash pass (no max-tracking; scores tiny).  qt pre-scaled in the qt GEMM.
// One block per (query, key-chunk of 98); 4 waves; 4 rows/iter/wave + tail.
// HR read exactly once.  (R12 loop structure; NCHUNK=8 halves per-block
// fixed costs while keeping 16 waves/CU residency.)
// ---------------------------------------------------------------------------
__global__ __launch_bounds__(256) void k_flash(const float4* __restrict__ HR,
                                               const float4* __restrict__ qt,
                                               float4* __restrict__ Cpart,
                                               float* __restrict__ Lp) {
    const int b     = blockIdx.x;
    const int qi    = b >> 3;
    const int chunk = b & 7;
    const size_t rowbase = (size_t)qi * KPQ + (size_t)chunk * KCHUNK;
    const int tid  = threadIdx.x;
    const int w    = tid >> 6;
    const int lane = tid & 63;

    const float4 qa = qt[qi * DF4 + lane];
    const float4 qb = qt[qi * DF4 + lane + 64];
    const float4 qc = qt[qi * DF4 + lane + 128];

    float l = 0.f;
    float4 c0 = make_float4(0.f, 0.f, 0.f, 0.f);
    float4 c1 = make_float4(0.f, 0.f, 0.f, 0.f);
    float4 c2 = make_float4(0.f, 0.f, 0.f, 0.f);

    int j = w;
    while (j + 12 < KCHUNK) {
        const float4* rA = HR + (rowbase + (size_t)j) * DF4;
        const float4* rB = HR + (rowbase + (size_t)(j + 4)) * DF4;
        const float4* rF = HR + (rowbase + (size_t)(j + 8)) * DF4;
        const float4* rG = HR + (rowbase + (size_t)(j + 12)) * DF4;
        const float4 a0 = rA[lane], a1 = rA[lane + 64], a2 = rA[lane + 128];
        const float4 b0 = rB[lane], b1 = rB[lane + 64], b2 = rB[lane + 128];
        const float4 f0 = rF[lane], f1 = rF[lane + 64], f2 = rF[lane + 128];
        const float4 g0 = rG[lane], g1 = rG[lane + 64], g2 = rG[lane + 128];
        float p1 = dot4f(qa, a0) + dot4f(qb, a1) + dot4f(qc, a2);
        float p2 = dot4f(qa, b0) + dot4f(qb, b1) + dot4f(qc, b2);
        float p3 = dot4f(qa, f0) + dot4f(qb, f1) + dot4f(qc, f2);
        float p4 = dot4f(qa, g0) + dot4f(qb, g1) + dot4f(qc, g2);
#pragma unroll
        for (int off = 32; off; off >>= 1) {
            p1 += __shfl_xor(p1, off, 64);
            p2 += __shfl_xor(p2, off, 64);
            p3 += __shfl_xor(p3, off, 64);
            p4 += __shfl_xor(p4, off, 64);
        }
        const float e1 = EXP2F(p1);
        const float e2 = EXP2F(p2);
        const float e3 = EXP2F(p3);
        const float e4 = EXP2F(p4);
        l += (e1 + e2) + (e3 + e4);
        c0.x = fmaf(e1, a0.x, fmaf(e2, b0.x, fmaf(e3, f0.x, fmaf(e4, g0.x, c0.x))));
        c0.y = fmaf(e1, a0.y, fmaf(e2, b0.y, fmaf(e3, f0.y, fmaf(e4, g0.y, c0.y))));
        c0.z = fmaf(e1, a0.z, fmaf(e2, b0.z, fmaf(e3, f0.z, fmaf(e4, g0.z, c0.z))));
        c0.w = fmaf(e1, a0.w, fmaf(e2, b0.w, fmaf(e3, f0.w, fmaf(e4, g0.w, c0.w))));
        c1.x = fmaf(e1, a1.x, fmaf(e2, b1.x, fmaf(e3, f1.x, fmaf(e4, g1.x, c1.x))));
        c1.y = fmaf(e1, a1.y, fmaf(e2, b1.y, fmaf(e3, f1.y, fmaf(e4, g1.y, c1.y))));
        c1.z = fmaf(e1, a1.z, fmaf(e2, b1.z, fmaf(e3, f1.z, fmaf(e4, g1.z, c1.z))));
        c1.w = fmaf(e1, a1.w, fmaf(e2, b1.w, fmaf(e3, f1.w, fmaf(e4, g1.w, c1.w))));
        c2.x = fmaf(e1, a2.x, fmaf(e2, b2.x, fmaf(e3, f2.x, fmaf(e4, g2.x, c2.x))));
        c2.y = fmaf(e1, a2.y, fmaf(e2, b2.y, fmaf(e3, f2.y, fmaf(e4, g2.y, c2.y))));
        c2.z = fmaf(e1, a2.z, fmaf(e2, b2.z, fmaf(e3, f2.z, fmaf(e4, g2.z, c2.z))));
        c2.w = fmaf(e1, a2.w, fmaf(e2, b2.w, fmaf(e3, f2.w, fmaf(e4, g2.w, c2.w))));
        j += 16;
    }
    while (j < KCHUNK) {
        const float4* rA = HR + (rowbase + (size_t)j) * DF4;
        const float4 a0 = rA[lane], a1 = rA[lane + 64], a2 = rA[lane + 128];
        float p1 = dot4f(qa, a0) + dot4f(qb, a1) + dot4f(qc, a2);
#pragma unroll
        for (int off = 32; off; off >>= 1) p1 += __shfl_xor(p1, off, 64);
        const float e1 = EXP2F(p1);
        l += e1;
        c0.x = fmaf(e1, a0.x, c0.x); c0.y = fmaf(e1, a0.y, c0.y);
        c0.z = fmaf(e1, a0.z, c0.z); c0.w = fmaf(e1, a0.w, c0.w);
        c1.x = fmaf(e1, a1.x, c1.x); c1.y = fmaf(e1, a1.y, c1.y);
        c1.z = fmaf(e1, a1.z, c1.z); c1.w = fmaf(e1, a1.w, c1.w);
        c2.x = fmaf(e1, a2.x, c2.x); c2.y = fmaf(e1, a2.y, c2.y);
        c2.z = fmaf(e1, a2.z, c2.z); c2.w = fmaf(e1, a2.w, c2.w);
        j += 4;
    }

    __shared__ __align__(16) float4 c_lds[4][DF4];
    __shared__ float l_lds[4];
    c_lds[w][lane]       = c0;
    c_lds[w][lane + 64]  = c1;
    c_lds[w][lane + 128] = c2;
    if (lane == 0) l_lds[w] = l;
    __syncthreads();

    if (tid < DF4) {
        float4 cc = make_float4(0.f, 0.f, 0.f, 0.f);
#pragma unroll
        for (int p = 0; p < 4; ++p) {
            const float4 cv = c_lds[p][tid];
            cc.x += cv.x; cc.y += cv.y; cc.z += cv.z; cc.w += cv.w;
        }
        Cpart[(size_t)b * DF4 + tid] = cc;
        if (tid == 0) Lp[b] = l_lds[0] + l_lds[1] + l_lds[2] + l_lds[3];
    }
}

// ---------------------------------------------------------------------------
// Combine: all chunk partials share reference 0 -> plain sums, then divide.
// ---------------------------------------------------------------------------
__global__ __launch_bounds__(192) void k_combine(const float4* __restrict__ Cpart,
                                                 const float* __restrict__ Lp,
                                                 float4* __restrict__ Cn) {
    const int qi = blockIdx.x;
    const int f  = threadIdx.x;
    float L = 0.f;
#pragma unroll
    for (int p = 0; p < NCHUNK; ++p) L += Lp[qi * NCHUNK + p];
    float4 c = make_float4(0.f, 0.f, 0.f, 0.f);
#pragma unroll
    for (int p = 0; p < NCHUNK; ++p) {
        const float4 v = Cpart[(size_t)(qi * NCHUNK + p) * DF4 + f];
        c.x += v.x; c.y += v.y; c.z += v.z; c.w += v.w;
    }
    const float inv = 1.f / L;
    c.x *= inv; c.y *= inv; c.z *= inv; c.w *= inv;
    Cn[(size_t)qi * DF4 + f] = c;
}

// ---------------------------------------------------------------------------
// LayerNorm: one block per query (256 threads, 3 elems each).
// ---------------------------------------------------------------------------
__global__ __launch_bounds__(256) void k_ln(const float* __restrict__ y,
                                            const float* __restrict__ gamma,
                                            const float* __restrict__ beta,
                                            float* __restrict__ out) {
    __shared__ float sp[4], ssp[4];
    const int qi = blockIdx.x;
    const int tid = threadIdx.x, w = tid >> 6, lane = tid & 63;
    const float* yr = y + (size_t)qi * D;
    const float v0 = yr[tid], v1 = yr[tid + 256], v2 = yr[tid + 512];
    float s  = v0 + v1 + v2;
    float ss = v0 * v0 + v1 * v1 + v2 * v2;
#pragma unroll
    for (int off = 32; off; off >>= 1) {
        s  += __shfl_xor(s, off, 64);
        ss += __shfl_xor(ss, off, 64);
    }
    if (lane == 0) { sp[w] = s; ssp[w] = ss; }
    __syncthreads();
    s  = sp[0] + sp[1] + sp[2] + sp[3];
    ss = ssp[0] + ssp[1] + ssp[2] + ssp[3];
    const float mu  = s * (1.f / 768.f);
    const float var = ss * (1.f / 768.f) - mu * mu;
    const float rs  = rsqrtf(var + 1e-5f);
    float* o = out + (size_t)qi * D;
    o[tid]       = (v0 - mu) * rs * gamma[tid]       + beta[tid];
    o[tid + 256] = (v1 - mu) * rs * gamma[tid + 256] + beta[tid + 256];
    o[tid + 512] = (v2 - mu) * rs * gamma[tid + 512] + beta[tid + 512];
}

extern "C" void kernel_launch(void* const* d_in, const int* in_sizes, int n_in,
                              void* d_out, int out_size, void* d_ws, size_t ws_size,
                              hipStream_t stream) {
    const float* LR    = (const float*)d_in[0];
    const float* HR    = (const float*)d_in[1];
    const float* Wq    = (const float*)d_in[2];
    const float* bq    = (const float*)d_in[3];
    const float* Wk    = (const float*)d_in[4];
    // d_in[5] = bk: unused (per-query constant on all scores; softmax-invariant)
    const float* Wv    = (const float*)d_in[6];
    const float* bv    = (const float*)d_in[7];
    const float* Wo    = (const float*)d_in[8];
    const float* bo    = (const float*)d_in[9];
    const float* gamma = (const float*)d_in[10];
    const float* beta  = (const float*)d_in[11];
    float* out = (float*)d_out;

    float* ws = (float*)d_ws;
    float* WqT   = ws;                  // 589824
    float* WvT   = ws + 589824;         // 589824
    float* WoT   = ws + 1179648;        // 589824
    float* qbuf  = ws + 1769472;        // 98304
    float* qtbuf = ws + 1867776;        // 98304
    float* Cpart = ws + 1966080;        // 1024*768 = 786432
    float* Lp    = ws + 2752512;        // 1024
    float* Cn    = ws + 2753536;        // 98304
    float* Xbuf  = ws + 2851840;        // 98304
    float* ybuf  = ws + 2950144;        // 98304

    // transpose Wq, Wv, Wo
    k_tr<<<dim3(144, 3), 256, 0, stream>>>(Wq, Wv, Wo, WqT, WvT, WoT);
    // q = LR @ Wq^T + bq
    k_gemm2<true, false, false><<<192, 512, 0, stream>>>(
        LR, (const float2*)WqT, (const float2*)bq, nullptr, (float2*)qbuf);
    // qt = (q @ Wk) * 1/sqrt(d)*log2e  (scale folded in)
    k_gemm2<false, false, true><<<192, 512, 0, stream>>>(
        qbuf, (const float2*)Wk, nullptr, nullptr, (float2*)qtbuf);
    // flash pass over HR (no max-tracking; shared reference 0)
    k_flash<<<NQ * NCHUNK, 256, 0, stream>>>((const float4*)HR, (const float4*)qtbuf,
                                             (float4*)Cpart, Lp);
    // combine chunk partials -> Cn
    k_combine<<<NQ, 192, 0, stream>>>((const float4*)Cpart, Lp, (float4*)Cn);
    // X = Cn @ Wv^T + bv
    k_gemm2<true, false, false><<<192, 512, 0, stream>>>(
        Cn, (const float2*)WvT, (const float2*)bv, nullptr, (float2*)Xbuf);
    // y = q + X @ Wo^T + bo
    k_gemm2<true, true, false><<<192, 512, 0, stream>>>(
        Xbuf, (const float2*)WoT, (const float2*)bo, (const float2*)qbuf, (float2*)ybuf);
    // LayerNorm
    k_ln<<<NQ, 256, 0, stream>>>(ybuf, gamma, beta, out);
}

// Round 16
// 99.425 us; speedup vs baseline: 1.1479x; 1.0180x over previous
//
#include <hip/hip_runtime.h>
#include <math.h>

#define D 768
#define DF2 384               // D / 2
#define DF4 192               // D / 4
#define NQ 128                // total queries
#define KPQ 784               // keys per query
#define NCHUNK 8              // key chunks per query
#define KCHUNK 98             // KPQ / NCHUNK

#define EXP2F(x) __builtin_amdgcn_exp2f(x)

typedef float vfloat4 __attribute__((ext_vector_type(4)));

__device__ __forceinline__ float4 ldnt(const float4* p) {
    vfloat4 v = __builtin_nontemporal_load(reinterpret_cast<const vfloat4*>(p));
    return make_float4(v.x, v.y, v.z, v.w);
}

__device__ __forceinline__ float dot4f(const float4 a, const float4 b) {
    return a.x * b.x + a.y * b.y + a.z * b.z + a.w * b.w;
}

// ---------------------------------------------------------------------------
// Transpose Wq, Wv, Wo (768x768) -> ws.  64x64 tiles, LDS +1 pad.  (proven R7)
// ---------------------------------------------------------------------------
__global__ __launch_bounds__(256) void k_tr(const float* __restrict__ Wq,
                                            const float* __restrict__ Wv,
                                            const float* __restrict__ Wo,
                                            float* __restrict__ WqT,
                                            float* __restrict__ WvT,
                                            float* __restrict__ WoT) {
    __shared__ float t[64][65];
    const float* src;
    float* dst;
    if (blockIdx.y == 0)      { src = Wq; dst = WqT; }
    else if (blockIdx.y == 1) { src = Wv; dst = WvT; }
    else                      { src = Wo; dst = WoT; }
    const int tr = blockIdx.x / 12, tc = blockIdx.x % 12;
    const int r0 = tr * 64, c0 = tc * 64;
    const int lr = threadIdx.x >> 6, lc = threadIdx.x & 63;
#pragma unroll
    for (int i = 0; i < 16; ++i)
        t[lr + i * 4][lc] = src[(size_t)(r0 + lr + i * 4) * D + c0 + lc];
    __syncthreads();
#pragma unroll
    for (int i = 0; i < 16; ++i)
        dst[(size_t)(c0 + lr + i * 4) * D + r0 + lc] = t[lc][lr + i * 4];
}

// ---------------------------------------------------------------------------
// Small GEMM, split-N x split-K (proven R7, Q=4, 192 blocks, 512 threads).
// Out[q][e] = sum_d A[q][d]*W[d][e] (+bias)(+res)(*scale).
// ---------------------------------------------------------------------------
template <bool BIAS, bool RES, bool SCALE>
__global__ __launch_bounds__(512) void k_gemm2(const float* __restrict__ A,
                                               const float2* __restrict__ W2,
                                               const float2* __restrict__ bias2,
                                               const float2* __restrict__ res2,
                                               float2* __restrict__ Out2) {
    __shared__ float2 part[8][4][64];
    const int ct  = blockIdx.x % 6;
    const int q0  = (blockIdx.x / 6) * 4;
    const int tid = threadIdx.x;
    const int ds  = __builtin_amdgcn_readfirstlane(tid >> 6);   // wave id 0..7
    const int c2  = tid & 63;
    const int e2  = ct * 64 + c2;
    const float* a0 = A + (size_t)q0 * D;
    const float* a1 = a0 + D;
    const float* a2 = a1 + D;
    const float* a3 = a2 + D;
    float2 acc0 = {0.f, 0.f}, acc1 = {0.f, 0.f}, acc2 = {0.f, 0.f}, acc3 = {0.f, 0.f};
    const int dbase = ds * 96;
#pragma unroll 8
    for (int i = 0; i < 96; ++i) {
        const int d = dbase + i;
        const float2 wv = W2[(size_t)d * DF2 + e2];
        const float x0 = a0[d], x1 = a1[d], x2 = a2[d], x3 = a3[d];
        acc0.x = fmaf(x0, wv.x, acc0.x); acc0.y = fmaf(x0, wv.y, acc0.y);
        acc1.x = fmaf(x1, wv.x, acc1.x); acc1.y = fmaf(x1, wv.y, acc1.y);
        acc2.x = fmaf(x2, wv.x, acc2.x); acc2.y = fmaf(x2, wv.y, acc2.y);
        acc3.x = fmaf(x3, wv.x, acc3.x); acc3.y = fmaf(x3, wv.y, acc3.y);
    }
    part[ds][0][c2] = acc0;
    part[ds][1][c2] = acc1;
    part[ds][2][c2] = acc2;
    part[ds][3][c2] = acc3;
    __syncthreads();
    if (tid < 256) {
        const int q = tid >> 6, c = tid & 63;
        float2 s = {0.f, 0.f};
#pragma unroll
        for (int p = 0; p < 8; ++p) {
            s.x += part[p][q][c].x;
            s.y += part[p][q][c].y;
        }
        if (BIAS) {
            const float2 b = bias2[ct * 64 + c];
            s.x += b.x; s.y += b.y;
        }
        if (RES) {
            const float2 r = res2[(size_t)(q0 + q) * DF2 + ct * 64 + c];
            s.x += r.x; s.y += r.y;
        }
        if (SCALE) {
            const float rsd2 = 0.036084391824351615f * 1.4426950408889634f; // 1/sqrt(768)*log2e
            s.x *= rsd2; s.y *= rsd2;
        }
        Out2[(size_t)(q0 + q) * DF2 + ct * 64 + c] = s;
    }
}

// ---------------------------------------------------------------------------
// Flash pass (no max-tracking; scores tiny).  qt pre-scaled in the qt GEMM.
// One block per (query, key-chunk of 98); 4 waves; 4 rows/iter/wave + tail.
// HR loaded NON-TEMPORAL (zero reuse; bypass the ~3.4 TB/s L3-hit path and
// stream from HBM at ~6.3 TB/s).  HR read exactly once.
// ---------------------------------------------------------------------------
__global__ __launch_bounds__(256) void k_flash(const float4* __restrict__ HR,
                                               const float4* __restrict__ qt,
                                               float4* __restrict__ Cpart,
                                               float* __restrict__ Lp) {
    const int b     = blockIdx.x;
    const int qi    = b >> 3;
    const int chunk = b & 7;
    const size_t rowbase = (size_t)qi * KPQ + (size_t)chunk * KCHUNK;
    const int tid  = threadIdx.x;
    const int w    = tid >> 6;
    const int lane = tid & 63;

    const float4 qa = qt[qi * DF4 + lane];
    const float4 qb = qt[qi * DF4 + lane + 64];
    const float4 qc = qt[qi * DF4 + lane + 128];

    float l = 0.f;
    float4 c0 = make_float4(0.f, 0.f, 0.f, 0.f);
    float4 c1 = make_float4(0.f, 0.f, 0.f, 0.f);
    float4 c2 = make_float4(0.f, 0.f, 0.f, 0.f);

    int j = w;
    while (j + 12 < KCHUNK) {
        const float4* rA = HR + (rowbase + (size_t)j) * DF4;
        const float4* rB = HR + (rowbase + (size_t)(j + 4)) * DF4;
        const float4* rF = HR + (rowbase + (size_t)(j + 8)) * DF4;
        const float4* rG = HR + (rowbase + (size_t)(j + 12)) * DF4;
        const float4 a0 = ldnt(rA + lane), a1 = ldnt(rA + lane + 64), a2 = ldnt(rA + lane + 128);
        const float4 b0 = ldnt(rB + lane), b1 = ldnt(rB + lane + 64), b2 = ldnt(rB + lane + 128);
        const float4 f0 = ldnt(rF + lane), f1 = ldnt(rF + lane + 64), f2 = ldnt(rF + lane + 128);
        const float4 g0 = ldnt(rG + lane), g1 = ldnt(rG + lane + 64), g2 = ldnt(rG + lane + 128);
        float p1 = dot4f(qa, a0) + dot4f(qb, a1) + dot4f(qc, a2);
        float p2 = dot4f(qa, b0) + dot4f(qb, b1) + dot4f(qc, b2);
        float p3 = dot4f(qa, f0) + dot4f(qb, f1) + dot4f(qc, f2);
        float p4 = dot4f(qa, g0) + dot4f(qb, g1) + dot4f(qc, g2);
#pragma unroll
        for (int off = 32; off; off >>= 1) {
            p1 += __shfl_xor(p1, off, 64);
            p2 += __shfl_xor(p2, off, 64);
            p3 += __shfl_xor(p3, off, 64);
            p4 += __shfl_xor(p4, off, 64);
        }
        const float e1 = EXP2F(p1);
        const float e2 = EXP2F(p2);
        const float e3 = EXP2F(p3);
        const float e4 = EXP2F(p4);
        l += (e1 + e2) + (e3 + e4);
        c0.x = fmaf(e1, a0.x, fmaf(e2, b0.x, fmaf(e3, f0.x, fmaf(e4, g0.x, c0.x))));
        c0.y = fmaf(e1, a0.y, fmaf(e2, b0.y, fmaf(e3, f0.y, fmaf(e4, g0.y, c0.y))));
        c0.z = fmaf(e1, a0.z, fmaf(e2, b0.z, fmaf(e3, f0.z, fmaf(e4, g0.z, c0.z))));
        c0.w = fmaf(e1, a0.w, fmaf(e2, b0.w, fmaf(e3, f0.w, fmaf(e4, g0.w, c0.w))));
        c1.x = fmaf(e1, a1.x, fmaf(e2, b1.x, fmaf(e3, f1.x, fmaf(e4, g1.x, c1.x))));
        c1.y = fmaf(e1, a1.y, fmaf(e2, b1.y, fmaf(e3, f1.y, fmaf(e4, g1.y, c1.y))));
        c1.z = fmaf(e1, a1.z, fmaf(e2, b1.z, fmaf(e3, f1.z, fmaf(e4, g1.z, c1.z))));
        c1.w = fmaf(e1, a1.w, fmaf(e2, b1.w, fmaf(e3, f1.w, fmaf(e4, g1.w, c1.w))));
        c2.x = fmaf(e1, a2.x, fmaf(e2, b2.x, fmaf(e3, f2.x, fmaf(e4, g2.x, c2.x))));
        c2.y = fmaf(e1, a2.y, fmaf(e2, b2.y, fmaf(e3, f2.y, fmaf(e4, g2.y, c2.y))));
        c2.z = fmaf(e1, a2.z, fmaf(e2, b2.z, fmaf(e3, f2.z, fmaf(e4, g2.z, c2.z))));
        c2.w = fmaf(e1, a2.w, fmaf(e2, b2.w, fmaf(e3, f2.w, fmaf(e4, g2.w, c2.w))));
        j += 16;
    }
    while (j < KCHUNK) {
        const float4* rA = HR + (rowbase + (size_t)j) * DF4;
        const float4 a0 = ldnt(rA + lane), a1 = ldnt(rA + lane + 64), a2 = ldnt(rA + lane + 128);
        float p1 = dot4f(qa, a0) + dot4f(qb, a1) + dot4f(qc, a2);
#pragma unroll
        for (int off = 32; off; off >>= 1) p1 += __shfl_xor(p1, off, 64);
        const float e1 = EXP2F(p1);
        l += e1;
        c0.x = fmaf(e1, a0.x, c0.x); c0.y = fmaf(e1, a0.y, c0.y);
        c0.z = fmaf(e1, a0.z, c0.z); c0.w = fmaf(e1, a0.w, c0.w);
        c1.x = fmaf(e1, a1.x, c1.x); c1.y = fmaf(e1, a1.y, c1.y);
        c1.z = fmaf(e1, a1.z, c1.z); c1.w = fmaf(e1, a1.w, c1.w);
        c2.x = fmaf(e1, a2.x, c2.x); c2.y = fmaf(e1, a2.y, c2.y);
        c2.z = fmaf(e1, a2.z, c2.z); c2.w = fmaf(e1, a2.w, c2.w);
        j += 4;
    }

    __shared__ __align__(16) float4 c_lds[4][DF4];
    __shared__ float l_lds[4];
    c_lds[w][lane]       = c0;
    c_lds[w][lane + 64]  = c1;
    c_lds[w][lane + 128] = c2;
    if (lane == 0) l_lds[w] = l;
    __syncthreads();

    if (tid < DF4) {
        float4 cc = make_float4(0.f, 0.f, 0.f, 0.f);
#pragma unroll
        for (int p = 0; p < 4; ++p) {
            const float4 cv = c_lds[p][tid];
            cc.x += cv.x; cc.y += cv.y; cc.z += cv.z; cc.w += cv.w;
        }
        Cpart[(size_t)b * DF4 + tid] = cc;
        if (tid == 0) Lp[b] = l_lds[0] + l_lds[1] + l_lds[2] + l_lds[3];
    }
}

// ---------------------------------------------------------------------------
// Combine: all chunk partials share reference 0 -> plain sums, then divide.
// ---------------------------------------------------------------------------
__global__ __launch_bounds__(192) void k_combine(const float4* __restrict__ Cpart,
                                                 const float* __restrict__ Lp,
                                                 float4* __restrict__ Cn) {
    const int qi = blockIdx.x;
    const int f  = threadIdx.x;
    float L = 0.f;
#pragma unroll
    for (int p = 0; p < NCHUNK; ++p) L += Lp[qi * NCHUNK + p];
    float4 c = make_float4(0.f, 0.f, 0.f, 0.f);
#pragma unroll
    for (int p = 0; p < NCHUNK; ++p) {
        const float4 v = Cpart[(size_t)(qi * NCHUNK + p) * DF4 + f];
        c.x += v.x; c.y += v.y; c.z += v.z; c.w += v.w;
    }
    const float inv = 1.f / L;
    c.x *= inv; c.y *= inv; c.z *= inv; c.w *= inv;
    Cn[(size_t)qi * DF4 + f] = c;
}

// ---------------------------------------------------------------------------
// LayerNorm: one block per query (256 threads, 3 elems each).
// ---------------------------------------------------------------------------
__global__ __launch_bounds__(256) void k_ln(const float* __restrict__ y,
                                            const float* __restrict__ gamma,
                                            const float* __restrict__ beta,
                                            float* __restrict__ out) {
    __shared__ float sp[4], ssp[4];
    const int qi = blockIdx.x;
    const int tid = threadIdx.x, w = tid >> 6, lane = tid & 63;
    const float* yr = y + (size_t)qi * D;
    const float v0 = yr[tid], v1 = yr[tid + 256], v2 = yr[tid + 512];
    float s  = v0 + v1 + v2;
    float ss = v0 * v0 + v1 * v1 + v2 * v2;
#pragma unroll
    for (int off = 32; off; off >>= 1) {
        s  += __shfl_xor(s, off, 64);
        ss += __shfl_xor(ss, off, 64);
    }
    if (lane == 0) { sp[w] = s; ssp[w] = ss; }
    __syncthreads();
    s  = sp[0] + sp[1] + sp[2] + sp[3];
    ss = ssp[0] + ssp[1] + ssp[2] + ssp[3];
    const float mu  = s * (1.f / 768.f);
    const float var = ss * (1.f / 768.f) - mu * mu;
    const float rs  = rsqrtf(var + 1e-5f);
    float* o = out + (size_t)qi * D;
    o[tid]       = (v0 - mu) * rs * gamma[tid]       + beta[tid];
    o[tid + 256] = (v1 - mu) * rs * gamma[tid + 256] + beta[tid + 256];
    o[tid + 512] = (v2 - mu) * rs * gamma[tid + 512] + beta[tid + 512];
}

extern "C" void kernel_launch(void* const* d_in, const int* in_sizes, int n_in,
                              void* d_out, int out_size, void* d_ws, size_t ws_size,
                              hipStream_t stream) {
    const float* LR    = (const float*)d_in[0];
    const float* HR    = (const float*)d_in[1];
    const float* Wq    = (const float*)d_in[2];
    const float* bq    = (const float*)d_in[3];
    const float* Wk    = (const float*)d_in[4];
    // d_in[5] = bk: unused (per-query constant on all scores; softmax-invariant)
    const float* Wv    = (const float*)d_in[6];
    const float* bv    = (const float*)d_in[7];
    const float* Wo    = (const float*)d_in[8];
    const float* bo    = (const float*)d_in[9];
    const float* gamma = (const float*)d_in[10];
    const float* beta  = (const float*)d_in[11];
    float* out = (float*)d_out;

    float* ws = (float*)d_ws;
    float* WqT   = ws;                  // 589824
    float* WvT   = ws + 589824;         // 589824
    float* WoT   = ws + 1179648;        // 589824
    float* qbuf  = ws + 1769472;        // 98304
    float* qtbuf = ws + 1867776;        // 98304
    float* Cpart = ws + 1966080;        // 1024*768 = 786432
    float* Lp    = ws + 2752512;        // 1024
    float* Cn    = ws + 2753536;        // 98304
    float* Xbuf  = ws + 2851840;        // 98304
    float* ybuf  = ws + 2950144;        // 98304

    // transpose Wq, Wv, Wo
    k_tr<<<dim3(144, 3), 256, 0, stream>>>(Wq, Wv, Wo, WqT, WvT, WoT);
    // q = LR @ Wq^T + bq
    k_gemm2<true, false, false><<<192, 512, 0, stream>>>(
        LR, (const float2*)WqT, (const float2*)bq, nullptr, (float2*)qbuf);
    // qt = (q @ Wk) * 1/sqrt(d)*log2e  (scale folded in)
    k_gemm2<false, false, true><<<192, 512, 0, stream>>>(
        qbuf, (const float2*)Wk, nullptr, nullptr, (float2*)qtbuf);
    // flash pass over HR (no max-tracking; shared reference 0; NT loads)
    k_flash<<<NQ * NCHUNK, 256, 0, stream>>>((const float4*)HR, (const float4*)qtbuf,
                                             (float4*)Cpart, Lp);
    // combine chunk partials -> Cn
    k_combine<<<NQ, 192, 0, stream>>>((const float4*)Cpart, Lp, (float4*)Cn);
    // X = Cn @ Wv^T + bv
    k_gemm2<true, false, false><<<192, 512, 0, stream>>>(
        Cn, (const float2*)WvT, (const float2*)bv, nullptr, (float2*)Xbuf);
    // y = q + X @ Wo^T + bo
    k_gemm2<true, true, false><<<192, 512, 0, stream>>>(
        Xbuf, (const float2*)WoT, (const float2*)bo, (const float2*)qbuf, (float2*)ybuf);
    // LayerNorm
    k_ln<<<NQ, 256, 0, stream>>>(ybuf, gamma, beta, out);
}